// Round 6
// baseline (412.112 us; speedup 1.0000x reference)
//
#include <hip/hip_runtime.h>

// Conv1d: x (32, 64, 16384) f32, w (64, 64, 3) f32, bias (64) f32
// -> out (32, 64, 16382) f32, VALID, stride 1.
// GEMM view: out[co][n] = sum_kappa A[co][kappa] * B[kappa][n] + bias[co]
//   kappa = kk*64 + ci (kk-major). B[kappa][n] = x[ci][n+kk]; the kk shift is
//   applied at LDS-read time (col+kk), so each x element is staged ONCE.
//
// R4 (vs R3, 125us rocprof): pipelined multi-subtile blocks.
//  - Each block: 1024 cols = 8 sub-tiles x 128, xt double-buffered (2x19KB).
//    Per sub-tile: load(next)->regs, MFMA(cur), cvt+write(next), barrier.
//    HBM latency hides under compute (T14 split); weight staging amortized 8x.
//  - Staging map: idx=(ci,col) col-fastest -> global loads coalesced AND LDS
//    writes at col-stride-1 across lanes = 36-word stride = 4-way conflicts
//    (R3's stride-4 write pattern was 16-32-way: 17.8M conflict cycles).
//  - A-fragments (24 x bf16x8 = 96 VGPR) + bias hoisted to registers once;
//    wl LDS is read only in the prologue. Bias folded into MFMA C-init.
//  - LDS 63.9KB -> 2 blocks/CU; __launch_bounds__(256,2) -> 256-reg budget
//    (total demand ~220, no spills; verify WRITE_SIZE stays ~137MB).

typedef __bf16 bf16x8 __attribute__((ext_vector_type(8)));
typedef float f32x16 __attribute__((ext_vector_type(16)));

#define C_IN 64
#define C_OUT 64
#define L_IN 16384
#define L_OUT 16382
#define NT 128           // cols per sub-tile
#define SUBT 8           // sub-tiles per block
#define BT (NT * SUBT)   // 1024 cols per block
#define PW 200           // wl row pitch (elems): 16B-aligned rows, conflict-free b128
#define XT_P 72          // xt row pitch: 144B = 16B-aligned, 36-word (=4-bank) stride
#define XT_COLS 132      // 128 cols + 3 halo + 1 pad
#define NLOAD 33         // 64*132/256 staging elems per thread (exact)

__global__ __launch_bounds__(256, 2) void conv1d_mfma(
    const float* __restrict__ x, const float* __restrict__ w,
    const float* __restrict__ bias, float* __restrict__ out) {
  __shared__ __align__(16) __bf16 wl[C_OUT * PW];        // 25600 B
  __shared__ __align__(16) __bf16 xtA[XT_COLS * XT_P];   // 19008 B
  __shared__ __align__(16) __bf16 xtB[XT_COLS * XT_P];   // 19008 B
  __shared__ float bias_s[C_OUT];                        // 256 B  (total 63872)

  const int t = threadIdx.x;
  const int bx = blockIdx.x;
  const int b = bx >> 4;        // batch
  const int tile = bx & 15;     // 1024-col tile
  const int l0 = tile * BT;
  const float* xb = x + (size_t)b * (C_IN * L_IN);

  // ---- weights -> LDS bf16, wl[co][kk*64+ci] (once per block, amortized 8x)
  for (int i = t; i < C_OUT * 192; i += 256) {
    int co = i / 192;
    int r = i - co * 192;
    int ci = r / 3;
    int kk = r - ci * 3;
    wl[co * PW + kk * 64 + ci] = (__bf16)w[i];
  }
  if (t < C_OUT) bias_s[t] = bias[t];

  const int lane = t & 63;
  const int wv = t >> 6;
  const int half = lane >> 5;
  const int ln = lane & 31;
  const int kh = half * 8;
  const int colbase = wv * 32 + ln;    // this lane's column within sub-tile

  // Staging: idx -> (ci = idx/132, col = idx%132). Consecutive lanes ->
  // consecutive cols: global loads coalesced (132-float runs), LDS writes at
  // col-stride-1 (36 words ~ 4 banks apart -> ~4-way, vs R3's 16-32-way).
#define STAGE_LOAD(BASE, SV)                                    \
  _Pragma("unroll") for (int k = 0; k < NLOAD; ++k) {           \
    int idx = t + k * 256;                                      \
    int ci = idx / XT_COLS;                                     \
    int col = idx - ci * XT_COLS;                               \
    int gc = (BASE) + col;                                      \
    gc = min(gc, L_IN - 1);  /* clamp: feeds only unstored cols */ \
    SV[k] = xb[(size_t)ci * L_IN + gc];                         \
  }

#define STAGE_WRITE(BUF, SV)                                    \
  _Pragma("unroll") for (int k = 0; k < NLOAD; ++k) {           \
    int idx = t + k * 256;                                      \
    int ci = idx / XT_COLS;                                     \
    int col = idx - ci * XT_COLS;                               \
    BUF[col * XT_P + ci] = (__bf16)SV[k];                       \
  }

  // ---- prologue: stage sub-tile 0 into xtA
  {
    float sv0[NLOAD];
    STAGE_LOAD(l0, sv0)
    STAGE_WRITE(xtA, sv0)
  }
  __syncthreads();

  // ---- hoist A fragments + bias into registers (static indices only)
  bf16x8 A0[12], A1[12];
#pragma unroll
  for (int s = 0; s < 12; ++s) {
    A0[s] = *(const bf16x8*)&wl[ln * PW + s * 16 + kh];
    A1[s] = *(const bf16x8*)&wl[(32 + ln) * PW + s * 16 + kh];
  }
  float bs0[16], bs1[16];
#pragma unroll
  for (int r = 0; r < 16; ++r) {
    int cl = 4 * half + (r & 3) + 8 * (r >> 2);
    bs0[r] = bias_s[cl];
    bs1[r] = bias_s[32 + cl];
  }

  // ---- 2-phase pipeline: load(SS+1) | compute(SS) | write(SS+1) | barrier
#define PHASE(CUR, NXT, SS, ISLAST)                                          \
  {                                                                          \
    float sv[NLOAD];                                                         \
    if (!(ISLAST)) { STAGE_LOAD(l0 + ((SS) + 1) * NT, sv) }                  \
    f32x16 acc0, acc1;                                                       \
    _Pragma("unroll") for (int r = 0; r < 16; ++r) {                         \
      acc0[r] = bs0[r];                                                      \
      acc1[r] = bs1[r];                                                      \
    }                                                                        \
    _Pragma("unroll") for (int s = 0; s < 12; ++s) {                         \
      int kap = s * 16 + kh;                                                 \
      int kk = kap >> 6;     /* uniform over the 8-elem fragment */          \
      int ci0 = kap & 63;                                                    \
      bf16x8 bf = *(const bf16x8*)&CUR[(colbase + kk) * XT_P + ci0];         \
      acc0 = __builtin_amdgcn_mfma_f32_32x32x16_bf16(A0[s], bf, acc0, 0, 0, 0); \
      acc1 = __builtin_amdgcn_mfma_f32_32x32x16_bf16(A1[s], bf, acc1, 0, 0, 0); \
    }                                                                        \
    if (!(ISLAST)) { STAGE_WRITE(NXT, sv) }                                  \
    {                                                                        \
      int ng = l0 + (SS) * NT + colbase;                                     \
      _Pragma("unroll") for (int r = 0; r < 16; ++r) {                       \
        int cl = 4 * half + (r & 3) + 8 * (r >> 2);                          \
        if ((SS) < SUBT - 1 || ng < L_OUT) {                                 \
          out[(size_t)(b * C_OUT + cl) * L_OUT + ng] = acc0[r];              \
          out[(size_t)(b * C_OUT + 32 + cl) * L_OUT + ng] = acc1[r];         \
        }                                                                    \
      }                                                                      \
    }                                                                        \
    __syncthreads();                                                         \
  }

  PHASE(xtA, xtB, 0, 0)
  PHASE(xtB, xtA, 1, 0)
  PHASE(xtA, xtB, 2, 0)
  PHASE(xtB, xtA, 3, 0)
  PHASE(xtA, xtB, 4, 0)
  PHASE(xtB, xtA, 5, 0)
  PHASE(xtA, xtB, 6, 0)
  PHASE(xtB, xtA, 7, 1)
#undef PHASE
#undef STAGE_LOAD
#undef STAGE_WRITE
}

extern "C" void kernel_launch(void* const* d_in, const int* in_sizes, int n_in,
                              void* d_out, int out_size, void* d_ws, size_t ws_size,
                              hipStream_t stream) {
  const float* x = (const float*)d_in[0];
  const float* w = (const float*)d_in[1];
  const float* bias = (const float*)d_in[2];
  float* out = (float*)d_out;
  // 32 batches * 16 tiles of 1024 columns = 512 blocks (2 per CU exactly)
  conv1d_mfma<<<dim3(32 * 16), dim3(256), 0, stream>>>(x, w, bias, out);
}

// Round 7
// 283.503 us; speedup vs baseline: 1.4536x; 1.4536x over previous
//
#include <hip/hip_runtime.h>

// Conv1d: x (32, 64, 16384) f32, w (64, 64, 3) f32, bias (64) f32
// -> out (32, 64, 16382) f32, VALID, stride 1.
// GEMM view: out[co][n] = sum_kappa A[co][kappa] * B[kappa][n] + bias[co]
//   kappa = kk*64 + ci (kk-major). B[kappa][n] = x[ci][n+kk]; kk shift applied
//   at LDS-read time (col+kk) so each x element is staged once.
//
// R7 = R3 (measured 125us, never spilled) + surgical fixes:
//  - REGISTER BUDGET BY CONSTRUCTION: R4 spilled because the allocator caps
//    arch VGPRs at 128 with 256-thr MFMA blocks (measured: VGPR_Count=128,
//    +151MB scratch writes). Here: sv[17] staging + 16 AGPR acc (one 32x32
//    tile per wave) + no A-hoisting => ~76 total regs. No spill possible.
//  - NT=64 cols/phase x 8 phases/block: weight staging amortized 8x; T14
//    split (issue loads -> MFMA(cur) -> barrier -> LDS write) hides HBM
//    latency under compute without double-buffering.
//  - Staging map col-fastest: LDS write bank stride 4 (4-way, ~free) vs
//    R3's stride-16 (16-way, 17.8M conflict cycles = 23% of kernel).
//  - LDS 34.8KB -> 4 blocks/CU; grid 1024 = 4*256 exactly resident.

typedef __bf16 bf16x8 __attribute__((ext_vector_type(8)));
typedef float f32x16 __attribute__((ext_vector_type(16)));

#define C_IN 64
#define C_OUT 64
#define L_IN 16384
#define L_OUT 16382
#define NT 64            // cols per phase
#define SUBT 8           // phases per block
#define BT (NT * SUBT)   // 512 cols per block
#define PW 200           // wl row pitch: 16B-aligned rows, conflict-free b128
#define XT_P 72          // xt row pitch: 144B = 16B-aligned b128, bank-stride 4
#define XT_COLS 68       // 64 cols + 2 halo + 2 pad; 64*68 = 17*256 exact
#define NLOAD 17         // staging elems per thread per phase

__global__ __launch_bounds__(256, 4) void conv1d_mfma(
    const float* __restrict__ x, const float* __restrict__ w,
    const float* __restrict__ bias, float* __restrict__ out) {
  __shared__ __align__(16) __bf16 wl[C_OUT * PW];      // 25600 B
  __shared__ __align__(16) __bf16 xt[XT_COLS * XT_P];  // 9792 B
  __shared__ float bias_s[C_OUT];                      // 256 B (total 35648)

  const int t = threadIdx.x;
  const int bx = blockIdx.x;
  const int b = bx >> 5;        // batch
  const int tile = bx & 31;     // 512-col tile
  const int l0 = tile * BT;
  const float* xb = x + (size_t)b * (C_IN * L_IN);

  // ---- weights -> LDS bf16, wl[co][kk*64+ci] (once per block, amortized 8x)
  for (int i = t; i < C_OUT * 192; i += 256) {
    int co = i / 192;
    int r = i - co * 192;
    int ci = r / 3;
    int kk = r - ci * 3;
    wl[co * PW + kk * 64 + ci] = (__bf16)w[i];
  }
  if (t < C_OUT) bias_s[t] = bias[t];

  const int lane = t & 63;
  const int wv = t >> 6;
  const int coh = wv >> 1;      // co-half   (wave tile: 32 co x 32 col)
  const int colh = wv & 1;      // col-half
  const int half = lane >> 5;   // k-half within fragment
  const int ln = lane & 31;
  const int kh = half * 8;

  // Staging map: idx = t + k*256 -> (ci = idx/68, col = idx%68).
  // Consecutive lanes -> consecutive cols: global loads coalesced (272B runs),
  // LDS writes bank-stride 4 (4-way max).
  float sv[NLOAD];
#pragma unroll
  for (int k = 0; k < NLOAD; ++k) {
    int idx = t + k * 256;
    int ci = idx / XT_COLS;
    int col = idx - ci * XT_COLS;
    int gc = min(l0 + col, L_IN - 1);
    sv[k] = xb[(size_t)ci * L_IN + gc];
  }
#pragma unroll
  for (int k = 0; k < NLOAD; ++k) {
    int idx = t + k * 256;
    int ci = idx / XT_COLS;
    int col = idx - ci * XT_COLS;
    xt[col * XT_P + ci] = (__bf16)sv[k];
  }
  __syncthreads();

  for (int ss = 0; ss < SUBT; ++ss) {
    // ---- T14: issue next phase's global loads BEFORE compute
    if (ss < SUBT - 1) {
#pragma unroll
      for (int k = 0; k < NLOAD; ++k) {
        int idx = t + k * 256;
        int ci = idx / XT_COLS;
        int col = idx - ci * XT_COLS;
        int gc = min(l0 + (ss + 1) * NT + col, L_IN - 1);  // clamp: feeds only
        sv[k] = xb[(size_t)ci * L_IN + gc];                // unstored cols
      }
    }

    // ---- MFMA on current xt: 12 k-steps (K = 3*64 = 192)
    f32x16 acc = {};
#pragma unroll
    for (int s = 0; s < 12; ++s) {
      int kap = s * 16 + kh;        // kappa of first fragment element
      int kk = kap >> 6;            // uniform over the 8-elem fragment
      int ci0 = kap & 63;
      bf16x8 av = *(const bf16x8*)&wl[(coh * 32 + ln) * PW + kap];
      bf16x8 bv = *(const bf16x8*)&xt[(colh * 32 + ln + kk) * XT_P + ci0];
      acc = __builtin_amdgcn_mfma_f32_32x32x16_bf16(av, bv, acc, 0, 0, 0);
    }

    // ---- store: C/D col = lane&31 -> n, row r -> co_local
    {
      int ng = l0 + ss * NT + colh * 32 + ln;
      bool tail = (tile == 31 && ss == SUBT - 1);   // wave-uniform
      if (!tail || ng < L_OUT) {
#pragma unroll
        for (int r = 0; r < 16; ++r) {
          int cl = 4 * half + (r & 3) + 8 * (r >> 2);
          int co = coh * 32 + cl;
          out[(size_t)(b * C_OUT + co) * L_OUT + ng] = acc[r] + bias_s[co];
        }
      }
    }

    __syncthreads();   // all waves done reading xt before overwrite
    if (ss < SUBT - 1) {
#pragma unroll
      for (int k = 0; k < NLOAD; ++k) {
        int idx = t + k * 256;
        int ci = idx / XT_COLS;
        int col = idx - ci * XT_COLS;
        xt[col * XT_P + ci] = (__bf16)sv[k];
      }
      __syncthreads(); // writes visible before next phase's MFMA
    }
  }
}

extern "C" void kernel_launch(void* const* d_in, const int* in_sizes, int n_in,
                              void* d_out, int out_size, void* d_ws, size_t ws_size,
                              hipStream_t stream) {
  const float* x = (const float*)d_in[0];
  const float* w = (const float*)d_in[1];
  const float* bias = (const float*)d_in[2];
  float* out = (float*)d_out;
  // 32 batches * 32 tiles of 512 columns = 1024 blocks = 4/CU, fully resident
  conv1d_mfma<<<dim3(32 * 32), dim3(256), 0, stream>>>(x, w, bias, out);
}